// Round 6
// baseline (470.695 us; speedup 1.0000x reference)
//
#include <hip/hip_runtime.h>
#include <hip/hip_bf16.h>
#include <math.h>

// Workspace layout (bytes). Proven-safe footprint is 984,064 B; the spill
// region is used ONLY if ws_size says it exists (runtime branch) — otherwise
// the proven atomic-keyed baseline path runs.
//   xb  : [4][1024][112] bf16   @ 0        (917,504)  conv input (fv | fv_max)
//   fo  : [4][1024]      f32    @ 917504   ( 16,384)  feat_o
//   am  : [4][512]       u64    @ 933888   ( 16,384)  argmax keys (fallback only)
//   sw  : [4][64][49]    f32    @ 933888   ( 50,176)  slice weights (after am dead)
//   fvp : [4][112][512]  float2 @ 984064 (1,835,008)  (fv_max, fv) spill — [b][m][c]
//         layout makes k_pool1's store fvp[wg] fully coalesced (wg has c fastest).
#define XB_OFF  0
#define FO_OFF  917504
#define AM_OFF  933888
#define SW_OFF  933888
#define FVP_OFF 984064
#define SPILL_NEED (FVP_OFF + 1835008)

// ---------------------------------------------------------------------------
// Spill path K1a: PURE streaming pool — wave per (b,m,c) map, linear 235 MB
// HBM read (wave n reads the n-th contiguous 1 KB map). Single coalesced
// 8 B float2 store per wave; NO scattered partial-line writes (the old xb
// scatter cost ~115 MB of hidden RMW traffic).
__global__ __launch_bounds__(256) void k_pool1(const float* __restrict__ oct,
                                               float2* __restrict__ fvp) {
    int wg = (blockIdx.x * 256 + threadIdx.x) >> 6;   // (b*112+m)*512+c
    int lane = threadIdx.x & 63;
    const float4* p = (const float4*)(oct + (size_t)wg * 256);
    float4 v = p[lane];
    float s  = v.x + v.y + v.z + v.w;
    float mx = fmaxf(fmaxf(v.x, v.y), fmaxf(v.z, v.w));
#pragma unroll
    for (int off = 32; off >= 1; off >>= 1) {
        s  += __shfl_xor(s, off);
        mx  = fmaxf(mx, __shfl_xor(mx, off));
    }
    if (lane == 0)
        fvp[wg] = make_float2(mx, s * (1.0f / 256.0f));
}

// Spill path K1b: exact-fp32 argmax + feat_o + bf16 xb production.
// Wave per (b,c); 3.7 MB cache-resident transposed read. np.argmax
// first-occurrence: in-lane strict > prefers smaller m; butterfly ties break
// toward smaller m. xb rows staged in LDS, then written as contiguous 896 B
// u32 bursts (4 adjacent c-rows per block).
__global__ __launch_bounds__(256) void k_pool2(const float2* __restrict__ fvp,
                                               __hip_bfloat16* __restrict__ xb,
                                               float* __restrict__ fo) {
    __shared__ unsigned int sfv[4][56];   // bf16 fv rows (u32-aligned)
    __shared__ unsigned int smx[4][56];   // bf16 fv_max rows
    int t = threadIdx.x, w = t >> 6, lane = t & 63;
    int wid = blockIdx.x * 4 + w;         // b*512+c  (no block straddles b)
    int b = wid >> 9, c = wid & 511;
    __hip_bfloat16* fvrow = (__hip_bfloat16*)sfv[w];
    __hip_bfloat16* mxrow = (__hip_bfloat16*)smx[w];
    // m0 = lane (<112 always), m1 = lane+64 (<112 iff lane<48)
    float2 v0 = fvp[((size_t)b * 112 + lane) * 512 + c];
    float k0 = v0.x, f0 = v0.y;
    fvrow[lane] = __float2bfloat16(f0);
    mxrow[lane] = __float2bfloat16(k0);
    float k1 = -INFINITY, f1 = -INFINITY;
    if (lane < 48) {
        float2 v1 = fvp[((size_t)b * 112 + lane + 64) * 512 + c];
        k1 = v1.x; f1 = v1.y;
        fvrow[lane + 64] = __float2bfloat16(f1);
        mxrow[lane + 64] = __float2bfloat16(k1);
    }
    float bk, bp; int bm;
    if (k1 > k0) { bk = k1; bm = lane + 64; bp = f1; }
    else         { bk = k0; bm = lane;      bp = f0; }
    float bf = fmaxf(f0, f1);
#pragma unroll
    for (int off = 32; off >= 1; off >>= 1) {
        float ok = __shfl_xor(bk, off);
        int   om = __shfl_xor(bm, off);
        float op = __shfl_xor(bp, off);
        if (ok > bk || (ok == bk && om < bm)) { bk = ok; bm = om; bp = op; }
        bf = fmaxf(bf, __shfl_xor(bf, off));
    }
    if (lane == 0) {
        fo[b * 1024 + c]       = bf;   // feat_o_avg = max_m fv (fp32 exact)
        fo[b * 1024 + 512 + c] = bp;   // feat_o_max = fv at argmax_m fv_max
    }
    __syncthreads();
    // coalesced xb write-out: rows c..c+3 are contiguous (896 B per region)
    int cbase = (blockIdx.x * 4) & 511;
    unsigned int* xo = (unsigned int*)xb;
    if (t < 224) {
        int row = t / 56, col = t % 56;
        xo[((size_t)b * 1024 + cbase + row) * 56 + col]       = sfv[row][col];
        xo[((size_t)b * 1024 + 512 + cbase + row) * 56 + col] = smx[row][col];
    }
}

// ---------------------------------------------------------------------------
// Fallback path (proven baseline): K0 zero keys, K1 atomic packed-key pool,
// K2 feat_o gather. Byte-identical logic to the 466 µs baseline.
__global__ __launch_bounds__(256) void k_init(unsigned long long* __restrict__ am) {
    am[blockIdx.x * 256 + threadIdx.x] = 0ULL;
}

__global__ __launch_bounds__(256) void k_pool(const float* __restrict__ oct,
                                              __hip_bfloat16* __restrict__ xb,
                                              unsigned long long* __restrict__ am) {
    int wg = (blockIdx.x * 256 + threadIdx.x) >> 6;   // (b*112+m)*512+c
    int lane = threadIdx.x & 63;
    const float4* p = (const float4*)(oct + (size_t)wg * 256);
    float4 v = p[lane];
    float s  = v.x + v.y + v.z + v.w;
    float mx = fmaxf(fmaxf(v.x, v.y), fmaxf(v.z, v.w));
#pragma unroll
    for (int off = 32; off >= 1; off >>= 1) {
        s  += __shfl_xor(s, off);
        mx  = fmaxf(mx, __shfl_xor(mx, off));
    }
    if (lane == 0) {
        int c  = wg & 511;
        int bm = wg >> 9;
        int m  = bm % 112;
        int b  = bm / 112;
        xb[((size_t)b * 1024 + c) * 112 + m]       = __float2bfloat16(s * (1.0f / 256.0f));
        xb[((size_t)b * 1024 + 512 + c) * 112 + m] = __float2bfloat16(mx);
        unsigned int u = __float_as_uint(mx);
        unsigned int key = (u & 0x80000000u) ? ~u : (u | 0x80000000u);
        unsigned long long pk = ((unsigned long long)key << 32) | (unsigned int)(111 - m);
        atomicMax(&am[b * 512 + c], pk);
    }
}

__global__ __launch_bounds__(256) void k_feato(const __hip_bfloat16* __restrict__ xb,
                                               const unsigned long long* __restrict__ am,
                                               float* __restrict__ fo) {
    int wid  = blockIdx.x * 4 + (threadIdx.x >> 6);   // b*512+c
    int lane = threadIdx.x & 63;
    int b = wid >> 9, c = wid & 511;
    const __hip_bfloat16* fvrow = xb + ((size_t)b * 1024 + c) * 112;
    float v0 = (lane < 112)      ? __bfloat162float(fvrow[lane])      : -INFINITY;
    float v1 = (lane + 64 < 112) ? __bfloat162float(fvrow[lane + 64]) : -INFINITY;
    float mxf = fmaxf(v0, v1);
#pragma unroll
    for (int off = 32; off >= 1; off >>= 1)
        mxf = fmaxf(mxf, __shfl_xor(mxf, off));
    if (lane == 0) {
        int mstar = 111 - (int)(unsigned int)(am[b * 512 + c] & 0xFFFFFFFFULL);
        fo[b * 1024 + c]       = mxf;
        fo[b * 1024 + 512 + c] = __bfloat162float(fvrow[mstar]);
    }
}

// ---------------------------------------------------------------------------
// K3: conv1d (Cin=1024, K=64, L=112 -> 49) — UNCHANGED proven version.
__global__ __launch_bounds__(256) void k_conv(const __hip_bfloat16* __restrict__ xb,
                                              const float* __restrict__ w1,
                                              const float* __restrict__ b1,
                                              float* __restrict__ sw) {
    __shared__ unsigned int xs[256 * 61];   // 62,464 B
    __shared__ float red[4][25];
    int bx = blockIdx.x;
    int lh = bx & 1, co = (bx >> 1) & 63, b = bx >> 7;
    int t = threadIdx.x, wv = t >> 6, lane = t & 63;
    int l0u = lh * 12;                      // uint offset of window start (bf16 l0=24*lh)
    float acc[25];
#pragma unroll
    for (int i = 0; i < 25; i++) acc[i] = 0.f;
    const unsigned int* gxb = (const unsigned int*)xb;
    for (int chunk = 0; chunk < 4; chunk++) {
        __syncthreads();
        for (int r = wv; r < 256; r += 4)
            if (lane < 56)
                xs[r * 61 + lane] = gxb[((size_t)b * 1024 + chunk * 256 + r) * 56 + lane];
        __syncthreads();
        int cil = wv * 64 + lane;
        int ci  = chunk * 256 + cil;
        const unsigned int* xu = xs + cil * 61 + l0u;
        float xf[88];
#pragma unroll
        for (int i = 0; i < 44; i++) {
            unsigned int u = xu[i];
            xf[2 * i]     = __uint_as_float(u << 16);
            xf[2 * i + 1] = __uint_as_float(u & 0xffff0000u);
        }
        const float* wrow = w1 + ((size_t)co * 1024 + ci) * 64;
#pragma unroll
        for (int kc = 0; kc < 4; kc++) {
            float ww[16];
#pragma unroll
            for (int j = 0; j < 16; j++) ww[j] = wrow[kc * 16 + j];
#pragma unroll
            for (int k = 0; k < 16; k++)
#pragma unroll
                for (int i = 0; i < 25; i++)
                    acc[i] += ww[k] * xf[kc * 16 + k + i];
        }
    }
#pragma unroll
    for (int i = 0; i < 25; i++) {
#pragma unroll
        for (int off = 32; off >= 1; off >>= 1)
            acc[i] += __shfl_xor(acc[i], off);
    }
    if (lane < 25) red[wv][lane] = acc[lane];
    __syncthreads();
    if (t < 25) {
        float s = red[0][t] + red[1][t] + red[2][t] + red[3][t] + b1[co];
        float sg = 1.f / (1.f + expf(-s));
        int l = lh * 24 + t;                // lh=0: 0..24; lh=1: 24..48 (24 dup-dropped)
        if (!(lh == 1 && t == 0))
            sw[(size_t)(b * 64 + co) * 49 + l] = sg;
    }
}

// ---------------------------------------------------------------------------
// K4: fused tail: convf+sigmoid -> rf (LDS), feat_f (LDS), head. One block/b.
// UNCHANGED from round-2/4 version that passed.
__global__ __launch_bounds__(256) void k_tail(const float* __restrict__ sw,
                                              const float* __restrict__ cw,
                                              const float* __restrict__ cb,
                                              const float* __restrict__ ff,
                                              const float* __restrict__ fo,
                                              const float* __restrict__ hw,
                                              const float* __restrict__ hb,
                                              float* __restrict__ out) {
    __shared__ float swl[3136];
    __shared__ float cwl[4160];
    __shared__ float rfl[169];
    __shared__ float ffl[512];
    __shared__ float hred[3][4];
    int b = blockIdx.x, t = threadIdx.x, w = t >> 6, lane = t & 63;
    for (int i = t; i < 3136; i += 256) swl[i] = sw[b * 3136 + i];
    for (int i = t; i < 4160; i += 256) cwl[i] = cw[i];
    __syncthreads();
    // convf (K=5, stride=4, pad=2) -> 1 + sigmoid
    if (t < 169) {
        int o = t / 13, l = t % 13;
        float s = cb[o];
        for (int i = 0; i < 64; i++) {
#pragma unroll
            for (int k = 0; k < 5; k++) {
                int pos = 4 * l + k - 2;
                if (pos >= 0 && pos < 49)
                    s += swl[i * 49 + pos] * cwl[(o * 64 + i) * 5 + k];
            }
        }
        rfl[t] = 1.f + 1.f / (1.f + expf(-s));
    }
    __syncthreads();
    // feat_f: thread t owns channels t and t+256; rfl reads broadcast (uniform).
    {
        float acc1 = 0.f, acc2 = 0.f;
        const float* r1 = ff + ((size_t)b * 512 + t) * 169;
        const float* r2 = r1 + 256 * 169;
        for (int pidx = 0; pidx < 169; ++pidx) {
            float rv = rfl[pidx];
            acc1 += r1[pidx] * rv;
            acc2 += r2[pidx] * rv;
        }
        ffl[t]       = acc1 * (1.0f / 169.0f);
        ffl[t + 256] = acc2 * (1.0f / 169.0f);
    }
    __syncthreads();
    // head Linear(1536 -> 3); feat = [ffl(512) | fo(1024)]
    {
        float s0 = 0.f, s1 = 0.f, s2 = 0.f;
#pragma unroll
        for (int rep = 0; rep < 6; ++rep) {
            int i = rep * 256 + t;
            float fv = (i < 512) ? ffl[i] : fo[b * 1024 + (i - 512)];
            s0 += fv * hw[i];
            s1 += fv * hw[1536 + i];
            s2 += fv * hw[3072 + i];
        }
#pragma unroll
        for (int off = 32; off >= 1; off >>= 1) {
            s0 += __shfl_xor(s0, off);
            s1 += __shfl_xor(s1, off);
            s2 += __shfl_xor(s2, off);
        }
        if (lane == 0) { hred[0][w] = s0; hred[1][w] = s1; hred[2][w] = s2; }
    }
    __syncthreads();
    if (t < 3)
        out[b * 3 + t] = hred[t][0] + hred[t][1] + hred[t][2] + hred[t][3] + hb[t];
}

// ---------------------------------------------------------------------------
extern "C" void kernel_launch(void* const* d_in, const int* in_sizes, int n_in,
                              void* d_out, int out_size, void* d_ws, size_t ws_size,
                              hipStream_t stream) {
    const float* ff  = (const float*)d_in[0];  // features_f [4,512,13,13]
    const float* oct = (const float*)d_in[1];  // oct_feats  [4,112,512,16,16]
    const float* w1  = (const float*)d_in[2];  // conv1d_w   [64,1024,64]
    const float* b1  = (const float*)d_in[3];  // conv1d_b   [64]
    const float* cw  = (const float*)d_in[4];  // convf_w    [13,64,5]
    const float* cb  = (const float*)d_in[5];  // convf_b    [13]
    const float* hw  = (const float*)d_in[6];  // head_w     [3,1536]
    const float* hb  = (const float*)d_in[7];  // head_b     [3]
    float* out = (float*)d_out;                // [4,3]
    char* ws = (char*)d_ws;
    __hip_bfloat16*     xb = (__hip_bfloat16*)(ws + XB_OFF);
    float*              fo = (float*)(ws + FO_OFF);
    unsigned long long* am = (unsigned long long*)(ws + AM_OFF);
    float*              sw = (float*)(ws + SW_OFF);

    if (ws_size >= (size_t)SPILL_NEED) {
        // streaming pool + exact-fp32 argmax (no atomics, no scattered stores)
        float2* fvp = (float2*)(ws + FVP_OFF);
        hipLaunchKernelGGL(k_pool1, dim3(57344), dim3(256), 0, stream, oct, fvp);
        hipLaunchKernelGGL(k_pool2, dim3(512),   dim3(256), 0, stream, fvp, xb, fo);
    } else {
        // proven baseline path within the 984,064 B footprint
        hipLaunchKernelGGL(k_init,  dim3(8),     dim3(256), 0, stream, am);
        hipLaunchKernelGGL(k_pool,  dim3(57344), dim3(256), 0, stream, oct, xb, am);
        hipLaunchKernelGGL(k_feato, dim3(512),   dim3(256), 0, stream, xb, am, fo);
    }
    hipLaunchKernelGGL(k_conv, dim3(512), dim3(256), 0, stream, xb, w1, b1, sw);
    hipLaunchKernelGGL(k_tail, dim3(4),   dim3(256), 0, stream, sw, cw, cb, ff, fo, hw, hb, out);
}